// Round 1
// baseline (74.661 us; speedup 1.0000x reference)
//
#include <hip/hip_runtime.h>

typedef _Float16 half8 __attribute__((ext_vector_type(8)));
typedef float f32x4 __attribute__((ext_vector_type(4)));

#define HH 96
#define WW 96
#define NN (HH * WW)        // 9216
#define T16 (NN / 16)       // 576 16-pixel tiles
#define BLK 512
#define AG (T16 / 8)        // 72 a-groups (8 a-tiles per block, one per wave)
#define NDC 9               // d-chunks: dc covers d = dc*32+1 .. dc*32+32 (+peels)
#define WIN 40              // window tiles: b_local = wave(0..7) + 1 + s(0..31) <= 39
#define NPART (AG * NDC)    // 648 block partials
#define ZTILE (WIN * 48)    // LDS index of the shared all-zero chunk (quad-3 B reads)
#define CNT_OFF 4096        // byte offset of counters in d_ws (past partials)

// Gaussian constants with log2(e) folded in (native v_exp_f32 is exp2):
#define CXY 0.0032059890f
#define CRGB 46.16624131f

// arg_ij as a K=32 f16 MFMA dot (layout verified absmax-0.0 R7/R8/R9):
//   U = [uh(5), uh(5), ul(5), Aih, Ail, 1, 1, 0..]   (uh/ul = f16 hi/lo split)
//   V = [vh(5), vl(5), vh(5), 1, 1, Ajh, Ajl, 0..]   (v = 2C-scaled values)
// Only h[0..18] of V are nonzero -> quad 3's B fragment (k=24..31) is all
// zeros. R12: stage only 3 quads/tile (LDS 43.5K->32.8K, -25% stage+read
// traffic); quad-3 lanes read a shared zero chunk via branchless
// (base,stride) addressing (stride 0) -- zero extra hot-loop instructions.
// Epilogue: sum w*K = ai*R + (1-2ai)*Q with R=S K, Q=S aj K.
// Symmetric coverage: d=0 w=1 (peeled, dc==0); d=1..287 w=2; d=288 w=1 for ALL a
// (each unordered pair hit twice). 576*(1+2*287+1)=576^2.
// HYGIENE (R11 lesson): A-fragment must be built branchlessly in a half8
// vector -- union writes through casted pointers / divergent branches demote
// it to scratch (R11: VGPR 40, FETCH 9.5 MB, 44 us, VALUBusy 11%).
// R12: finalize fused via last-block-done. partials are agent-scope atomic
// stores/loads (bypass the non-coherent per-XCD L2s); counters are TWO-level
// (per-dc 72-way then 9-way) to avoid single-address contention (R4 lesson --
// no single-address FP atomics; int counters at 72-way fan-in are ~0.5 us).
// The last block replays the original finalize reduction ORDER exactly
// (256 threads, stride-256 loop, shfl tree, 4-term wsum tree) => bit-exact.
// No cooperative launch (R10: never executes).

__device__ __forceinline__ void pix_data(
    const float* __restrict__ image, const float* __restrict__ probs, int p,
    float& fy, float& fx, float& r, float& g, float& b, float& A, float& a)
{
    const int y = p / WW;
    fy = (float)y; fx = (float)(p - y * WW);
    r = image[p]; g = image[NN + p]; b = image[2 * NN + p]; a = probs[p];
    A = -CXY * fmaf(fy, fy, fx * fx) - CRGB * fmaf(r, r, fmaf(g, g, b * b));
}

__global__ __launch_bounds__(BLK, 6) void crf_mfma7(
    const float* __restrict__ probs, const float* __restrict__ image,
    float* __restrict__ partials, int* __restrict__ cnt,
    float* __restrict__ out)
{
    __shared__ uint4 sv[WIN * 48 + 16];  // 30.25 KB: 3 quads/tile + zero chunk
    __shared__ float sa[WIN * 16];       // aj for the window
    __shared__ float wsum[8];
    __shared__ int lastflag;

    const int g = blockIdx.x, dc = blockIdx.y;
    const int tid = threadIdx.x, lane = tid & 63, wave = tid >> 6;
    const int quad = lane >> 4, col = lane & 15;
    const int wb = g * 8 + dc * 32;   // window base tile (mod T16)

    // ---- Stage window: compute V fragments (3 quads only) into LDS. ----
    for (int t = tid; t < WIN * 16; t += BLK) {
        int tile = wb + (t >> 4); if (tile >= T16) tile -= T16;
        const int j = tile * 16 + (t & 15);
        float fy, fx, r, gg, b, Aj, aj;
        pix_data(image, probs, j, fy, fx, r, gg, b, Aj, aj);
        const float vv[5] = {2.0f * CXY * fy, 2.0f * CXY * fx,
                             2.0f * CRGB * r, 2.0f * CRGB * gg, 2.0f * CRGB * b};
        union { _Float16 h[24]; uint4 q[3]; } V;
#pragma unroll
        for (int k = 0; k < 24; ++k) V.h[k] = (_Float16)0.0f;
#pragma unroll
        for (int d = 0; d < 5; ++d) {
            const _Float16 vh = (_Float16)vv[d];
            const _Float16 vl = (_Float16)(vv[d] - (float)vh);
            V.h[d] = vh; V.h[5 + d] = vl; V.h[10 + d] = vh;
        }
        const _Float16 Ah = (_Float16)Aj, Al = (_Float16)(Aj - (float)Ah);
        V.h[15] = (_Float16)1.0f; V.h[16] = (_Float16)1.0f; V.h[17] = Ah; V.h[18] = Al;
#pragma unroll
        for (int q = 0; q < 3; ++q) sv[(t >> 4) * 48 + q * 16 + (t & 15)] = V.q[q];
        sa[t] = aj;
    }
    if (tid < 16) {                      // shared zero chunk for quad-3 lanes
        uint4 z; z.x = 0u; z.y = 0u; z.z = 0u; z.w = 0u;
        sv[ZTILE + tid] = z;
    }

    // ---- Per-wave prologue: A fragment, branchless (register-guaranteed). ----
    const int a_tile = g * 8 + wave;          // < 576 always
    const int ip = a_tile * 16 + col;
    float fy, fx, r, gg, b, Ai, dum;
    pix_data(image, probs, ip, fy, fx, r, gg, b, Ai, dum);
    half8 Av;
    {
        const float uv[5] = {fy, fx, r, gg, b};
        _Float16 uh[5], ul[5];
#pragma unroll
        for (int d = 0; d < 5; ++d) {
            uh[d] = (_Float16)uv[d];
            ul[d] = (_Float16)(uv[d] - (float)uh[d]);
        }
        const _Float16 Aih = (_Float16)Ai, Ail = (_Float16)(Ai - (float)Aih);
        const _Float16 z = (_Float16)0.0f, one = (_Float16)1.0f;
        // A[j] = U[quad*8 + j]; U per comment above. Ternaries -> v_cndmask.
        Av[0] = quad == 0 ? uh[0] : quad == 1 ? uh[3] : quad == 2 ? Ail : z;
        Av[1] = quad == 0 ? uh[1] : quad == 1 ? uh[4] : quad == 2 ? one : z;
        Av[2] = quad == 0 ? uh[2] : quad == 1 ? ul[0] : quad == 2 ? one : z;
        Av[3] = quad == 0 ? uh[3] : quad == 1 ? ul[1] : z;
        Av[4] = quad == 0 ? uh[4] : quad == 1 ? ul[2] : z;
        Av[5] = quad == 0 ? uh[0] : quad == 1 ? ul[3] : z;
        Av[6] = quad == 0 ? uh[1] : quad == 1 ? ul[4] : z;
        Av[7] = quad == 0 ? uh[2] : quad == 1 ? Aih : z;
    }
    // Epilogue row data: rows r2 -> i = a_tile*16 + quad*4 + r2 (verified C/D map).
    const float4 aiv = *(const float4*)(probs + a_tile * 16 + quad * 4);
    const float air[4] = {aiv.x, aiv.y, aiv.z, aiv.w};

    // Branchless B addressing: quads 0..2 walk the window, quad 3 reads the
    // fixed zero chunk (stride 0). addr strength-reduces to one v_add per s.
    const int bbase = (quad < 3) ? (quad * 16 + col) : (ZTILE + col);
    const int bstep = (quad < 3) ? 48 : 0;

    f32x4 R2 = {0.0f, 0.0f, 0.0f, 0.0f}, Q2 = {0.0f, 0.0f, 0.0f, 0.0f};  // w=2
    f32x4 R1 = {0.0f, 0.0f, 0.0f, 0.0f}, Q1 = {0.0f, 0.0f, 0.0f, 0.0f};  // w=1
    __syncthreads();

    const int nmain = (dc == NDC - 1) ? 31 : 32;   // dc=8 peels d=288
#pragma unroll 2
    for (int s = 0; s < nmain; ++s) {
        const int bl = wave + 1 + s;              // 1..39
        union { uint4 q; half8 h; } B;
        B.q = sv[bbase + bl * bstep];
        f32x4 c0 = {0.0f, 0.0f, 0.0f, 0.0f};
        const f32x4 dd = __builtin_amdgcn_mfma_f32_16x16x32_f16(Av, B.h, c0, 0, 0, 0);
        const float aj = sa[bl * 16 + col];
#pragma unroll
        for (int r2 = 0; r2 < 4; ++r2) {
            const float K = __builtin_amdgcn_exp2f(dd[r2]);
            R2[r2] += K;
            Q2[r2] = fmaf(aj, K, Q2[r2]);
        }
    }
    // Peeled weight-1 iterations (block-uniform branches).
    if (dc == NDC - 1 || dc == 0) {
        const int bl = (dc == 0) ? wave : wave + 32;   // d=0 diag / d=288
        union { uint4 q; half8 h; } B;
        B.q = sv[bbase + bl * bstep];
        f32x4 c0 = {0.0f, 0.0f, 0.0f, 0.0f};
        const f32x4 dd = __builtin_amdgcn_mfma_f32_16x16x32_f16(Av, B.h, c0, 0, 0, 0);
        const float aj = sa[bl * 16 + col];
#pragma unroll
        for (int r2 = 0; r2 < 4; ++r2) {
            const float K = __builtin_amdgcn_exp2f(dd[r2]);
            R1[r2] += K;
            Q1[r2] = fmaf(aj, K, Q1[r2]);
        }
    }

    // Apply per-row factors: sum w*K*(ai + aj*(1-2ai)) = ai*R + (1-2ai)*Q.
    float s4 = 0.0f;
#pragma unroll
    for (int r2 = 0; r2 < 4; ++r2) {
        const float Rt = fmaf(2.0f, R2[r2], R1[r2]);
        const float Qt = fmaf(2.0f, Q2[r2], Q1[r2]);
        const float ci = fmaf(-2.0f, air[r2], 1.0f);
        s4 += fmaf(air[r2], Rt, ci * Qt);
    }
    for (int off = 32; off > 0; off >>= 1)
        s4 += __shfl_down(s4, off, 64);
    if (lane == 0) wsum[wave] = s4;
    __syncthreads();

    // ---- Fused finalize: last-block-done (R12). ----
    if (tid == 0) {
        float bs = 0.0f;
#pragma unroll
        for (int w = 0; w < 8; ++w) bs += wsum[w];
        // Agent-scope store bypasses the per-XCD L2 (non-coherent).
        __hip_atomic_store(&partials[dc * AG + g], bs,
                           __ATOMIC_RELAXED, __HIP_MEMORY_SCOPE_AGENT);
        __threadfence();
        int last = 0;
        const int o1 = __hip_atomic_fetch_add(&cnt[dc], 1,
                           __ATOMIC_RELAXED, __HIP_MEMORY_SCOPE_AGENT);
        if (o1 == AG - 1) {
            const int o2 = __hip_atomic_fetch_add(&cnt[NDC], 1,
                               __ATOMIC_RELAXED, __HIP_MEMORY_SCOPE_AGENT);
            last = (o2 == NDC - 1);
        }
        lastflag = last;
    }
    __syncthreads();
    if (lastflag) {                        // block-uniform branch
        __threadfence();
        float s = 0.0f;
        if (tid < 256) {
            // EXACT replica of the old finalize kernel's reduction order.
            for (int t = tid; t < NPART; t += 256)
                s += __hip_atomic_load(&partials[t],
                         __ATOMIC_RELAXED, __HIP_MEMORY_SCOPE_AGENT);
            for (int off = 32; off > 0; off >>= 1)
                s += __shfl_down(s, off, 64);
            if ((tid & 63) == 0) wsum[tid >> 6] = s;
        }
        __syncthreads();
        if (tid == 0)
            out[0] = ((wsum[0] + wsum[1]) + (wsum[2] + wsum[3])) * (1.0f / (float)NN);
    }
}

extern "C" void kernel_launch(void* const* d_in, const int* in_sizes, int n_in,
                              void* d_out, int out_size, void* d_ws, size_t ws_size,
                              hipStream_t stream) {
    const float* probs = (const float*)d_in[0];  // [1,2,96,96] fp32
    const float* image = (const float*)d_in[1];  // [1,3,96,96] fp32
    float* out = (float*)d_out;                  // [1] fp32
    float* partials = (float*)d_ws;              // NPART floats
    int* cnt = (int*)((char*)d_ws + CNT_OFF);    // NDC+1 ints (ws is poisoned!)

    hipMemsetAsync(cnt, 0, 64, stream);          // graph-capturable, 64 B
    crf_mfma7<<<dim3(AG, NDC), dim3(BLK), 0, stream>>>(probs, image, partials,
                                                       cnt, out);
}

// Round 2
// 66.722 us; speedup vs baseline: 1.1190x; 1.1190x over previous
//
#include <hip/hip_runtime.h>

typedef _Float16 half8 __attribute__((ext_vector_type(8)));
typedef float f32x4 __attribute__((ext_vector_type(4)));

#define HH 96
#define WW 96
#define NN (HH * WW)        // 9216
#define T16 (NN / 16)       // 576 16-pixel tiles
#define BLK 512
#define AG (T16 / 8)        // 72 a-groups (8 a-tiles per block, one per wave)
#define NDC 9               // d-chunks: dc covers d = dc*32+1 .. dc*32+32 (+peels)
#define WIN 40              // window tiles: b_local = wave(0..7) + 1 + s(0..31) <= 39
#define NPART (AG * NDC)    // 648 block partials
#define ZTILE ((WIN + 1) * 48)      // LDS index of zero chunk (after the pad tile)
#define SVSZ  ((WIN + 1) * 48 + 16) // 40 data tiles + 1 prefetch-pad tile + zero chunk

// Gaussian constants with log2(e) folded in (native v_exp_f32 is exp2):
#define CXY 0.0032059890f
#define CRGB 46.16624131f

// arg_ij as a K=32 f16 MFMA dot (layout verified absmax-0.0 R7/R8/R9):
//   U = [uh(5), uh(5), ul(5), Aih, Ail, 1, 1, 0..]   (uh/ul = f16 hi/lo split)
//   V = [vh(5), vl(5), vh(5), 1, 1, Ajh, Ajl, 0..]   (v = 2C-scaled values)
// Only h[0..18] of V are nonzero -> quad 3's B fragment (k=24..31) is all
// zeros: stage 3 quads/tile (validated bit-exact R12); quad-3 lanes read a
// shared zero chunk via branchless (base,stride=0) addressing.
// Epilogue: sum w*K = ai*R + (1-2ai)*Q with R=S K, Q=S aj K.
// Symmetric coverage: d=0 w=1 (peeled, dc==0); d=1..287 w=2; d=288 w=1 for ALL a
// (each unordered pair hit twice). 576*(1+2*287+1)=576^2.
// HYGIENE (R11): A-fragment built branchlessly in a half8 vector -- union
// writes through casted pointers / divergent branches demote it to scratch.
// R12 lesson: fused last-block-done finalize REGRESSED +9us (per-block
// agent fences serialize at XCD L2s). Two-kernel structure is cheaper.
// R13: (a) 4 blocks/CU -- LDS 34.4KB + launch_bounds(512,8) (VGPR<=64);
//      (b) software prefetch of B(s+1)/aj(s+1) breaks the per-iteration
//          ds_read(~120cy)->MFMA->exp serial chain; sv/sa padded by one
//          tile so the last prefetch overruns into a pad, not OOB.
// No single-address atomics (R4). No cooperative launch (R10).

__device__ __forceinline__ void pix_data(
    const float* __restrict__ image, const float* __restrict__ probs, int p,
    float& fy, float& fx, float& r, float& g, float& b, float& A, float& a)
{
    const int y = p / WW;
    fy = (float)y; fx = (float)(p - y * WW);
    r = image[p]; g = image[NN + p]; b = image[2 * NN + p]; a = probs[p];
    A = -CXY * fmaf(fy, fy, fx * fx) - CRGB * fmaf(r, r, fmaf(g, g, b * b));
}

__global__ __launch_bounds__(BLK, 8) void crf_mfma8(
    const float* __restrict__ probs, const float* __restrict__ image,
    float* __restrict__ partials)
{
    __shared__ uint4 sv[SVSZ];           // 31 KB: 3 quads/tile + pad + zero chunk
    __shared__ float sa[(WIN + 1) * 16]; // aj for the window (+prefetch pad)
    __shared__ float wsum[8];

    const int g = blockIdx.x, dc = blockIdx.y;
    const int tid = threadIdx.x, lane = tid & 63, wave = tid >> 6;
    const int quad = lane >> 4, col = lane & 15;
    const int wb = g * 8 + dc * 32;   // window base tile (mod T16)

    // ---- Stage window: compute V fragments (3 quads only) into LDS. ----
    for (int t = tid; t < WIN * 16; t += BLK) {
        int tile = wb + (t >> 4); if (tile >= T16) tile -= T16;
        const int j = tile * 16 + (t & 15);
        float fy, fx, r, gg, b, Aj, aj;
        pix_data(image, probs, j, fy, fx, r, gg, b, Aj, aj);
        const float vv[5] = {2.0f * CXY * fy, 2.0f * CXY * fx,
                             2.0f * CRGB * r, 2.0f * CRGB * gg, 2.0f * CRGB * b};
        union { _Float16 h[24]; uint4 q[3]; } V;
#pragma unroll
        for (int k = 0; k < 24; ++k) V.h[k] = (_Float16)0.0f;
#pragma unroll
        for (int d = 0; d < 5; ++d) {
            const _Float16 vh = (_Float16)vv[d];
            const _Float16 vl = (_Float16)(vv[d] - (float)vh);
            V.h[d] = vh; V.h[5 + d] = vl; V.h[10 + d] = vh;
        }
        const _Float16 Ah = (_Float16)Aj, Al = (_Float16)(Aj - (float)Ah);
        V.h[15] = (_Float16)1.0f; V.h[16] = (_Float16)1.0f; V.h[17] = Ah; V.h[18] = Al;
#pragma unroll
        for (int q = 0; q < 3; ++q) sv[(t >> 4) * 48 + q * 16 + (t & 15)] = V.q[q];
        sa[t] = aj;
    }
    if (tid < 16) {                      // shared zero chunk for quad-3 lanes
        uint4 z; z.x = 0u; z.y = 0u; z.z = 0u; z.w = 0u;
        sv[ZTILE + tid] = z;
    }

    // ---- Per-wave prologue: A fragment, branchless (register-guaranteed). ----
    const int a_tile = g * 8 + wave;          // < 576 always
    const int ip = a_tile * 16 + col;
    float fy, fx, r, gg, b, Ai, dum;
    pix_data(image, probs, ip, fy, fx, r, gg, b, Ai, dum);
    half8 Av;
    {
        const float uv[5] = {fy, fx, r, gg, b};
        _Float16 uh[5], ul[5];
#pragma unroll
        for (int d = 0; d < 5; ++d) {
            uh[d] = (_Float16)uv[d];
            ul[d] = (_Float16)(uv[d] - (float)uh[d]);
        }
        const _Float16 Aih = (_Float16)Ai, Ail = (_Float16)(Ai - (float)Aih);
        const _Float16 z = (_Float16)0.0f, one = (_Float16)1.0f;
        // A[j] = U[quad*8 + j]; U per comment above. Ternaries -> v_cndmask.
        Av[0] = quad == 0 ? uh[0] : quad == 1 ? uh[3] : quad == 2 ? Ail : z;
        Av[1] = quad == 0 ? uh[1] : quad == 1 ? uh[4] : quad == 2 ? one : z;
        Av[2] = quad == 0 ? uh[2] : quad == 1 ? ul[0] : quad == 2 ? one : z;
        Av[3] = quad == 0 ? uh[3] : quad == 1 ? ul[1] : z;
        Av[4] = quad == 0 ? uh[4] : quad == 1 ? ul[2] : z;
        Av[5] = quad == 0 ? uh[0] : quad == 1 ? ul[3] : z;
        Av[6] = quad == 0 ? uh[1] : quad == 1 ? ul[4] : z;
        Av[7] = quad == 0 ? uh[2] : quad == 1 ? Aih : z;
    }
    // Epilogue row data: rows r2 -> i = a_tile*16 + quad*4 + r2 (verified C/D map).
    const float4 aiv = *(const float4*)(probs + a_tile * 16 + quad * 4);
    const float air[4] = {aiv.x, aiv.y, aiv.z, aiv.w};

    // Branchless B addressing: quads 0..2 walk the window, quad 3 reads the
    // fixed zero chunk (stride 0).
    const int bbase = (quad < 3) ? (quad * 16 + col) : (ZTILE + col);
    const int bstep = (quad < 3) ? 48 : 0;

    f32x4 R2 = {0.0f, 0.0f, 0.0f, 0.0f}, Q2 = {0.0f, 0.0f, 0.0f, 0.0f};  // w=2
    f32x4 R1 = {0.0f, 0.0f, 0.0f, 0.0f}, Q1 = {0.0f, 0.0f, 0.0f, 0.0f};  // w=1
    __syncthreads();

    const int nmain = (dc == NDC - 1) ? 31 : 32;   // dc=8 peels d=288

    // Software-pipelined main loop: B(s+1)/aj(s+1) prefetched into registers
    // while MFMA+exp of s runs. Last prefetch lands in the pad tile (safe).
    int baddr = bbase + (wave + 1) * bstep;
    int saddr = (wave + 1) * 16 + col;
    uint4 bq = sv[baddr];
    float ajv = sa[saddr];
#pragma unroll 2
    for (int s = 0; s < nmain; ++s) {
        const uint4 bq_n = sv[baddr + bstep];
        const float aj_n = sa[saddr + 16];
        union { uint4 q; half8 h; } B;
        B.q = bq;
        f32x4 c0 = {0.0f, 0.0f, 0.0f, 0.0f};
        const f32x4 dd = __builtin_amdgcn_mfma_f32_16x16x32_f16(Av, B.h, c0, 0, 0, 0);
#pragma unroll
        for (int r2 = 0; r2 < 4; ++r2) {
            const float K = __builtin_amdgcn_exp2f(dd[r2]);
            R2[r2] += K;
            Q2[r2] = fmaf(ajv, K, Q2[r2]);
        }
        bq = bq_n; ajv = aj_n;
        baddr += bstep; saddr += 16;
    }
    // Peeled weight-1 iterations (block-uniform branches).
    if (dc == NDC - 1 || dc == 0) {
        const int bl = (dc == 0) ? wave : wave + 32;   // d=0 diag / d=288
        union { uint4 q; half8 h; } B;
        B.q = sv[bbase + bl * bstep];
        f32x4 c0 = {0.0f, 0.0f, 0.0f, 0.0f};
        const f32x4 dd = __builtin_amdgcn_mfma_f32_16x16x32_f16(Av, B.h, c0, 0, 0, 0);
        const float aj = sa[bl * 16 + col];
#pragma unroll
        for (int r2 = 0; r2 < 4; ++r2) {
            const float K = __builtin_amdgcn_exp2f(dd[r2]);
            R1[r2] += K;
            Q1[r2] = fmaf(aj, K, Q1[r2]);
        }
    }

    // Apply per-row factors: sum w*K*(ai + aj*(1-2ai)) = ai*R + (1-2ai)*Q.
    float s4 = 0.0f;
#pragma unroll
    for (int r2 = 0; r2 < 4; ++r2) {
        const float Rt = fmaf(2.0f, R2[r2], R1[r2]);
        const float Qt = fmaf(2.0f, Q2[r2], Q1[r2]);
        const float ci = fmaf(-2.0f, air[r2], 1.0f);
        s4 += fmaf(air[r2], Rt, ci * Qt);
    }
    for (int off = 32; off > 0; off >>= 1)
        s4 += __shfl_down(s4, off, 64);
    if (lane == 0) wsum[wave] = s4;
    __syncthreads();
    if (tid == 0) {
        float bs = 0.0f;
#pragma unroll
        for (int w = 0; w < 8; ++w) bs += wsum[w];
        partials[dc * AG + g] = bs;
    }
}

__global__ __launch_bounds__(256) void crf_finalize_kernel(
    const float* __restrict__ partials, float* __restrict__ out)
{
    const int tid = threadIdx.x;
    float s = 0.0f;
    for (int t = tid; t < NPART; t += 256)
        s += partials[t];
    for (int off = 32; off > 0; off >>= 1)
        s += __shfl_down(s, off, 64);
    __shared__ float wsum[4];
    if ((tid & 63) == 0) wsum[tid >> 6] = s;
    __syncthreads();
    if (tid == 0)
        out[0] = ((wsum[0] + wsum[1]) + (wsum[2] + wsum[3])) * (1.0f / (float)NN);
}

extern "C" void kernel_launch(void* const* d_in, const int* in_sizes, int n_in,
                              void* d_out, int out_size, void* d_ws, size_t ws_size,
                              hipStream_t stream) {
    const float* probs = (const float*)d_in[0];  // [1,2,96,96] fp32
    const float* image = (const float*)d_in[1];  // [1,3,96,96] fp32
    float* out = (float*)d_out;                  // [1] fp32
    float* partials = (float*)d_ws;              // NPART floats

    crf_mfma8<<<dim3(AG, NDC), dim3(BLK), 0, stream>>>(probs, image, partials);
    crf_finalize_kernel<<<dim3(1), dim3(256), 0, stream>>>(partials, out);
}

// Round 3
// 65.563 us; speedup vs baseline: 1.1388x; 1.0177x over previous
//
#include <hip/hip_runtime.h>

typedef _Float16 half8 __attribute__((ext_vector_type(8)));
typedef float f32x4 __attribute__((ext_vector_type(4)));

#define HH 96
#define WW 96
#define NN (HH * WW)        // 9216
#define T16 (NN / 16)       // 576 16-pixel tiles
#define BLK 512
#define AG (T16 / 8)        // 72 a-groups (8 a-tiles per block, one per wave)
#define NDC 9               // d-chunks: dc covers d = dc*32+1 .. dc*32+32 (+peels)
#define WIN 40              // window tiles: b_local = wave(0..7) + 1 + s(0..31) <= 39
#define NPART (AG * NDC)    // 648 block partials

// Gaussian constants with log2(e) folded in (native v_exp_f32 is exp2):
#define CXY 0.0032059890f
#define CRGB 46.16624131f

// arg_ij as a K=32 f16 MFMA dot (layout verified absmax-0.0 R7/R8/R9):
//   U = [uh(5), uh(5), ul(5), Aih, Ail, 1, 1, 0..]   (uh/ul = f16 hi/lo split)
//   V = [vh(5), vl(5), vh(5), 1, 1, Ajh, Ajl, 0..]   (v = 2C-scaled values)
// Epilogue: sum w*K = ai*R + (1-2ai)*Q with R=Σ K, Q=Σ aj K.
// Symmetric coverage: d=0 w=1 (peeled, dc==0); d=1..287 w=2; d=288 w=1 for ALL a
// (each unordered pair hit twice). 576*(1+2*287+1)=576^2.
// HYGIENE (R11 lesson): A-fragment must be built branchlessly in a half8
// vector — union writes through casted pointers / divergent branches demote
// it to scratch (R11: VGPR 40, FETCH 9.5 MB, 44 µs, VALUBusy 11%).
// No single-address atomics (R4). No cooperative launch (R10: never executes).
//
// SESSION FLOOR EVIDENCE (R12-R14): this exact structure measured 64.8/65.5 µs.
// R12: last-block-done fused finalize (agent atomics + threadfence per block)
//      REGRESSED +9 µs — per-block fences/writebacks cost far more than the
//      saved dispatch. Two-kernel structure is cheaper. Do not re-fuse.
// R13: 3-quad LDS compression + 4 blk/CU launch_bounds + register SW-prefetch
//      of B(s+1): NULL (66.7 vs 65.5). Grid is 648 blocks ≈ 2.5/CU — all
//      blocks are co-resident already at 43.5 KB LDS (cap 3/CU), and 5-6
//      waves/SIMD already hide the ds_read→MFMA chain. Occupancy/prefetch
//      are not the bottleneck.
// R14: timed window decomposition: every rocprof top-5 slot in all rounds is
//      the harness's 268 MB workspace poison-fill (~39.5 µs, 85% of achievable
//      HBM BW) + reset dispatches + graph gaps; the crf kernel (floor ~6 µs:
//      43.8M exp2 on the trans pipe, ~18 cy/iter on the LDS port) never
//      enters the top-5. The window is harness-overhead-bound; kernel-side
//      micro-opts move dur_us by less than bench noise (±1-2 µs).
// Finer dc-chunking (NDC 9→18) for tail balance was rejected: it reorders the
// partial-sum groupings and risks the bit-exact absmax-0.0 gate for ≤2-3 µs.

__device__ __forceinline__ void pix_data(
    const float* __restrict__ image, const float* __restrict__ probs, int p,
    float& fy, float& fx, float& r, float& g, float& b, float& A, float& a)
{
    const int y = p / WW;
    fy = (float)y; fx = (float)(p - y * WW);
    r = image[p]; g = image[NN + p]; b = image[2 * NN + p]; a = probs[p];
    A = -CXY * fmaf(fy, fy, fx * fx) - CRGB * fmaf(r, r, fmaf(g, g, b * b));
}

__global__ __launch_bounds__(BLK, 6) void crf_mfma6(
    const float* __restrict__ probs, const float* __restrict__ image,
    float* __restrict__ partials)
{
    __shared__ uint4 sv[WIN * 64];   // 40 KB: V fragments for the window
    __shared__ float sa[WIN * 16];   // aj for the window
    __shared__ float wsum[8];

    const int g = blockIdx.x, dc = blockIdx.y;
    const int tid = threadIdx.x, lane = tid & 63, wave = tid >> 6;
    const int quad = lane >> 4, col = lane & 15;
    const int wb = g * 8 + dc * 32;   // window base tile (mod T16)

    // ---- Stage window: compute V fragments straight into LDS. ----
    for (int t = tid; t < WIN * 16; t += BLK) {
        int tile = wb + (t >> 4); if (tile >= T16) tile -= T16;
        const int j = tile * 16 + (t & 15);
        float fy, fx, r, gg, b, Aj, aj;
        pix_data(image, probs, j, fy, fx, r, gg, b, Aj, aj);
        const float vv[5] = {2.0f * CXY * fy, 2.0f * CXY * fx,
                             2.0f * CRGB * r, 2.0f * CRGB * gg, 2.0f * CRGB * b};
        union { _Float16 h[32]; uint4 q[4]; } V;
#pragma unroll
        for (int k = 0; k < 32; ++k) V.h[k] = (_Float16)0.0f;
#pragma unroll
        for (int d = 0; d < 5; ++d) {
            const _Float16 vh = (_Float16)vv[d];
            const _Float16 vl = (_Float16)(vv[d] - (float)vh);
            V.h[d] = vh; V.h[5 + d] = vl; V.h[10 + d] = vh;
        }
        const _Float16 Ah = (_Float16)Aj, Al = (_Float16)(Aj - (float)Ah);
        V.h[15] = (_Float16)1.0f; V.h[16] = (_Float16)1.0f; V.h[17] = Ah; V.h[18] = Al;
#pragma unroll
        for (int q = 0; q < 4; ++q) sv[(t >> 4) * 64 + q * 16 + (t & 15)] = V.q[q];
        sa[t] = aj;
    }

    // ---- Per-wave prologue: A fragment, branchless (register-guaranteed). ----
    const int a_tile = g * 8 + wave;          // < 576 always
    const int ip = a_tile * 16 + col;
    float fy, fx, r, gg, b, Ai, dum;
    pix_data(image, probs, ip, fy, fx, r, gg, b, Ai, dum);
    half8 Av;
    {
        const float uv[5] = {fy, fx, r, gg, b};
        _Float16 uh[5], ul[5];
#pragma unroll
        for (int d = 0; d < 5; ++d) {
            uh[d] = (_Float16)uv[d];
            ul[d] = (_Float16)(uv[d] - (float)uh[d]);
        }
        const _Float16 Aih = (_Float16)Ai, Ail = (_Float16)(Ai - (float)Aih);
        const _Float16 z = (_Float16)0.0f, one = (_Float16)1.0f;
        // A[j] = U[quad*8 + j]; U per comment above. Ternaries -> v_cndmask.
        Av[0] = quad == 0 ? uh[0] : quad == 1 ? uh[3] : quad == 2 ? Ail : z;
        Av[1] = quad == 0 ? uh[1] : quad == 1 ? uh[4] : quad == 2 ? one : z;
        Av[2] = quad == 0 ? uh[2] : quad == 1 ? ul[0] : quad == 2 ? one : z;
        Av[3] = quad == 0 ? uh[3] : quad == 1 ? ul[1] : z;
        Av[4] = quad == 0 ? uh[4] : quad == 1 ? ul[2] : z;
        Av[5] = quad == 0 ? uh[0] : quad == 1 ? ul[3] : z;
        Av[6] = quad == 0 ? uh[1] : quad == 1 ? ul[4] : z;
        Av[7] = quad == 0 ? uh[2] : quad == 1 ? Aih : z;
    }
    // Epilogue row data: rows r2 -> i = a_tile*16 + quad*4 + r2 (verified C/D map).
    const float4 aiv = *(const float4*)(probs + a_tile * 16 + quad * 4);
    const float air[4] = {aiv.x, aiv.y, aiv.z, aiv.w};

    f32x4 R2 = {0.0f, 0.0f, 0.0f, 0.0f}, Q2 = {0.0f, 0.0f, 0.0f, 0.0f};  // w=2
    f32x4 R1 = {0.0f, 0.0f, 0.0f, 0.0f}, Q1 = {0.0f, 0.0f, 0.0f, 0.0f};  // w=1
    __syncthreads();

    const int nmain = (dc == NDC - 1) ? 31 : 32;   // dc=8 peels d=288
#pragma unroll 2
    for (int s = 0; s < nmain; ++s) {
        const int bl = wave + 1 + s;              // 1..39
        union { uint4 q; half8 h; } B;
        B.q = sv[bl * 64 + quad * 16 + col];
        f32x4 c0 = {0.0f, 0.0f, 0.0f, 0.0f};
        const f32x4 dd = __builtin_amdgcn_mfma_f32_16x16x32_f16(Av, B.h, c0, 0, 0, 0);
        const float aj = sa[bl * 16 + col];
#pragma unroll
        for (int r2 = 0; r2 < 4; ++r2) {
            const float K = __builtin_amdgcn_exp2f(dd[r2]);
            R2[r2] += K;
            Q2[r2] = fmaf(aj, K, Q2[r2]);
        }
    }
    // Peeled weight-1 iterations (block-uniform branches).
    if (dc == NDC - 1 || dc == 0) {
        const int bl = (dc == 0) ? wave : wave + 32;   // d=0 diag / d=288
        union { uint4 q; half8 h; } B;
        B.q = sv[bl * 64 + quad * 16 + col];
        f32x4 c0 = {0.0f, 0.0f, 0.0f, 0.0f};
        const f32x4 dd = __builtin_amdgcn_mfma_f32_16x16x32_f16(Av, B.h, c0, 0, 0, 0);
        const float aj = sa[bl * 16 + col];
#pragma unroll
        for (int r2 = 0; r2 < 4; ++r2) {
            const float K = __builtin_amdgcn_exp2f(dd[r2]);
            R1[r2] += K;
            Q1[r2] = fmaf(aj, K, Q1[r2]);
        }
    }

    // Apply per-row factors: sum w*K*(ai + aj*(1-2ai)) = ai*R + (1-2ai)*Q.
    float s4 = 0.0f;
#pragma unroll
    for (int r2 = 0; r2 < 4; ++r2) {
        const float Rt = fmaf(2.0f, R2[r2], R1[r2]);
        const float Qt = fmaf(2.0f, Q2[r2], Q1[r2]);
        const float ci = fmaf(-2.0f, air[r2], 1.0f);
        s4 += fmaf(air[r2], Rt, ci * Qt);
    }
    for (int off = 32; off > 0; off >>= 1)
        s4 += __shfl_down(s4, off, 64);
    if (lane == 0) wsum[wave] = s4;
    __syncthreads();
    if (tid == 0) {
        float bs = 0.0f;
#pragma unroll
        for (int w = 0; w < 8; ++w) bs += wsum[w];
        partials[dc * AG + g] = bs;
    }
}

__global__ __launch_bounds__(256) void crf_finalize_kernel(
    const float* __restrict__ partials, float* __restrict__ out)
{
    const int tid = threadIdx.x;
    float s = 0.0f;
    for (int t = tid; t < NPART; t += 256)
        s += partials[t];
    for (int off = 32; off > 0; off >>= 1)
        s += __shfl_down(s, off, 64);
    __shared__ float wsum[4];
    if ((tid & 63) == 0) wsum[tid >> 6] = s;
    __syncthreads();
    if (tid == 0)
        out[0] = ((wsum[0] + wsum[1]) + (wsum[2] + wsum[3])) * (1.0f / (float)NN);
}

extern "C" void kernel_launch(void* const* d_in, const int* in_sizes, int n_in,
                              void* d_out, int out_size, void* d_ws, size_t ws_size,
                              hipStream_t stream) {
    const float* probs = (const float*)d_in[0];  // [1,2,96,96] fp32
    const float* image = (const float*)d_in[1];  // [1,3,96,96] fp32
    float* out = (float*)d_out;                  // [1] fp32
    float* partials = (float*)d_ws;              // NPART floats

    crf_mfma6<<<dim3(AG, NDC), dim3(BLK), 0, stream>>>(probs, image, partials);
    crf_finalize_kernel<<<dim3(1), dim3(256), 0, stream>>>(partials, out);
}